// Round 1
// baseline (1000.105 us; speedup 1.0000x reference)
//
#include <hip/hip_runtime.h>
#include <math.h>

#define NPTS 4096
#define BLK 128
#define V 64
#define NPROJ 256
#define NBATCH 32

// R9: ONE shared 4096-float LDS buffer (16 KiB/block, was 32 KiB), software-
// pipelined between the two waves. LDS was the occupancy binder (32 KiB ->
// 5 blocks/CU = 10 waves = 21% occ, VALUBusy 61%); halving it doubles
// resident blocks (10 blocks/CU, 20 waves, VGPR 84 < 102 cap of
// __launch_bounds__(128,5)).
// Pipeline: buffer ownership alternates per "slot"; while wave 0 runs its
// LDS round k, wave 1 runs its in-register stages of round k-1, and vice
// versa; one __syncthreads per slot (19 total). Intra-wave write->read
// ordering within a round is still lgkmcnt (no barrier), exactly as the
// verified R8 kernel. Sort network and all layouts are unchanged:
// Layouts (element idx, 12 bits; T=wave-lane 6b, c=chunk 4b, l=comp 2b):
//   A: T=idx[11:6], c=idx[5:2]                (regs = idx[5:0])
//   B: T={idx[11:10],idx[5:2]}, c=idx[9:6]    (regs = {idx[9:6],idx[1:0]})
//   C: T=idx[9:4],  c={idx[11:10],idx[3:2]}   (regs = {idx[11:10],idx[3:0]})
// float4-slot placement: A/B: slot=(T<<4)|(c^(T&15)); C: slot=(T<<4)|(c^(T>>2&15)).
// All patterns bank-even (8 dwords/bank per b128) and bijective (verified).
// Normalized bitonic: merges 2..64 in-reg; m128/m256 via shfl_xor (DPP);
// m512..m4096 via LDS with reversal fused into the layout-entry read.
// Wave 1 publishes sorted y into the SAME buffer at the end; wave 0 diffs.

__device__ __forceinline__ void cmpex_asc(float& a, float& b) {
    const float lo = fminf(a, b), hi = fmaxf(a, b);
    a = lo; b = hi;
}

template<int JB, int JL>
__device__ __forceinline__ void stages(float* v) {
#pragma unroll
    for (int r = 0; r < V; ++r)
        if ((r & JB) == 0) cmpex_asc(v[r], v[r | JB]);
    if constexpr (JB > JL) stages<(JB >> 1), JL>(v);
}

template<int MASK>
__device__ __forceinline__ void rev_inreg(float* v) {
    constexpr int S = (MASK + 1) >> 1;
#pragma unroll
    for (int r = 0; r < V; ++r) {
        if ((r & S) == 0) {
            const float a = v[r], b = v[r ^ MASK];
            v[r] = fminf(a, b);
            v[r ^ MASK] = fmaxf(a, b);
        }
    }
}

// Reversal across thread-pair (xor XM), registers reversed (r <-> 63-r).
template<int XM>
__device__ __forceinline__ void rev_shfl(float* v, bool hi) {
#pragma unroll
    for (int r = 0; r < 32; ++r) {
        const float pa = __shfl_xor(v[63 - r], XM, 64);
        const float pb = __shfl_xor(v[r], XM, 64);
        v[r]      = hi ? fmaxf(v[r], pa)      : fminf(v[r], pa);
        v[63 - r] = hi ? fmaxf(v[63 - r], pb) : fminf(v[63 - r], pb);
    }
}
// Same-register cross-thread stage (xor XM).
template<int XM>
__device__ __forceinline__ void stage_shfl(float* v, bool hi) {
#pragma unroll
    for (int r = 0; r < V; ++r) {
        const float q = __shfl_xor(v[r], XM, 64);
        v[r] = hi ? fmaxf(v[r], q) : fminf(v[r], q);
    }
}

// A->B and B->A scatter-write (same formula, symmetric).
__device__ __forceinline__ void write_AB(float* s, const float* v, int sAB, int t15) {
    float4* s4 = (float4*)s;
#pragma unroll
    for (int c = 0; c < 16; ++c)
        s4[sAB | (c << 4) | (t15 ^ c)] =
            make_float4(v[4*c], v[4*c+1], v[4*c+2], v[4*c+3]);
}
// Natural (own-slot) write, A/B-resident layout.
__device__ __forceinline__ void write_own(float* s, const float* v, int t, int t15) {
    float4* s4 = (float4*)s;
#pragma unroll
    for (int c = 0; c < 16; ++c)
        s4[(t << 4) | (c ^ t15)] =
            make_float4(v[4*c], v[4*c+1], v[4*c+2], v[4*c+3]);
}
// Own-slot read, valid for A- and B-resident phases.
__device__ __forceinline__ void read_own(const float* s, float* v, int t, int t15) {
    const float4* s4 = (const float4*)s;
#pragma unroll
    for (int c = 0; c < 16; ++c) {
        const float4 f = s4[(t << 4) | (c ^ t15)];
        v[4*c] = f.x; v[4*c+1] = f.y; v[4*c+2] = f.z; v[4*c+3] = f.w;
    }
}
// B-entry read fused with reversal: own + partner (t^PM, c^CM, comps
// reversed). Keep side: chunk bit KB, or thread-uniform thi when KB==0.
template<int PM, int CM, int KB>
__device__ __forceinline__ void read_rev_B(const float* s, float* v, int t, int t15, bool thi) {
    const float4* s4 = (const float4*)s;
    const int pt = t ^ PM, pt15 = t15 ^ (PM & 15);
#pragma unroll
    for (int c = 0; c < 16; ++c) {
        const float4 o = s4[(t << 4) | (c ^ t15)];
        const float4 q = s4[(pt << 4) | ((c ^ CM) ^ pt15)];
        const bool mx = KB ? ((c & KB) != 0) : thi;
        v[4*c+0] = mx ? fmaxf(o.x, q.w) : fminf(o.x, q.w);
        v[4*c+1] = mx ? fmaxf(o.y, q.z) : fminf(o.y, q.z);
        v[4*c+2] = mx ? fmaxf(o.z, q.y) : fminf(o.z, q.y);
        v[4*c+3] = mx ? fmaxf(o.w, q.x) : fminf(o.w, q.x);
    }
}
// A->C scatter-write.
__device__ __forceinline__ void write_AC(float* s, const float* v, int t15, int qAC) {
    float4* s4 = (float4*)s;
#pragma unroll
    for (int c = 0; c < 16; ++c)
        s4[(t15 << 6) | ((c >> 2) << 4) | (qAC ^ (c & 3))] =
            make_float4(v[4*c], v[4*c+1], v[4*c+2], v[4*c+3]);
}
// C-entry read fused with m4096 reversal (partner t^63, c^15, keep c&8).
__device__ __forceinline__ void read_rev_C(const float* s, float* v, int t, int th) {
    const float4* s4 = (const float4*)s;
    const int pt = t ^ 63, pth = th ^ 15;
#pragma unroll
    for (int c = 0; c < 16; ++c) {
        const float4 o = s4[(t << 4) | (c ^ th)];
        const float4 q = s4[(pt << 4) | ((c ^ 15) ^ pth)];
        const bool mx = (c & 8) != 0;
        v[4*c+0] = mx ? fmaxf(o.x, q.w) : fminf(o.x, q.w);
        v[4*c+1] = mx ? fmaxf(o.y, q.z) : fminf(o.y, q.z);
        v[4*c+2] = mx ? fmaxf(o.z, q.y) : fminf(o.z, q.y);
        v[4*c+3] = mx ? fmaxf(o.w, q.x) : fminf(o.w, q.x);
    }
}
// C->B scatter-write.
__device__ __forceinline__ void write_CB(float* s, const float* v, int sCB, int qCB) {
    float4* s4 = (float4*)s;
#pragma unroll
    for (int c = 0; c < 16; ++c)
        s4[((c >> 2) << 8) | sCB | ((c & 3) << 4) | (qCB ^ (c & 3))] =
            make_float4(v[4*c], v[4*c+1], v[4*c+2], v[4*c+3]);
}

__device__ __forceinline__ void load_project(const float* base, float* v,
                                             float p0, float p1, float p2) {
    const float4* b4 = (const float4*)base;
#pragma unroll
    for (int g = 0; g < 16; ++g) {
        float4 a = b4[g * 3 + 0], c = b4[g * 3 + 1], d = b4[g * 3 + 2];
        v[4*g+0] = a.x * p0 + a.y * p1 + a.z * p2;
        v[4*g+1] = a.w * p0 + c.x * p1 + c.y * p2;
        v[4*g+2] = c.z * p0 + c.w * p1 + d.x * p2;
        v[4*g+3] = d.y * p0 + d.z * p1 + d.w * p2;
    }
}

__global__ __launch_bounds__(BLK, 5) void swd_kernel(
    const float* __restrict__ x, const float* __restrict__ y,
    const float* __restrict__ theta, const float* __restrict__ rot,
    float* __restrict__ per_batch) {
    __shared__ float buf[NPTS];   // 16 KiB — shared between the two waves

    const int t = threadIdx.x & 63;       // wave lane
    const int wave = threadIdx.x >> 6;    // 0: x, 1: y
    const int p = blockIdx.x;
    const int b = blockIdx.y;

    const float t0 = theta[p * 3 + 0], t1 = theta[p * 3 + 1], t2 = theta[p * 3 + 2];
    const float* R = rot + b * 9;
    const float p0 = t0 * R[0] + t1 * R[3] + t2 * R[6];
    const float p1 = t0 * R[1] + t1 * R[4] + t2 * R[7];
    const float p2 = t0 * R[2] + t1 * R[5] + t2 * R[8];

    const float* src = wave ? y : x;

    float v[V];
    load_project(src + (size_t)b * NPTS * 3 + (size_t)t * V * 3, v, p0, p1, p2);

    const int t15 = t & 15;
    const int sAB = (t >> 4) << 8;
    const int qAC = ((t >> 4) << 2) ^ t15;
    const int th  = (t >> 2) & 15;
    const int sCB = (t & 3) << 6;
    const int qCB = (t >> 2) ^ ((t & 3) << 2);
    const bool hi1  = (t & 1) != 0;
    const bool hi2  = (t & 2) != 0;
    const bool hi16 = (t & 16) != 0;

    // ---- merges 2..256: fully in-register / DPP, both waves concurrently
    rev_inreg<1>(v);
    rev_inreg<3>(v);  stages<1, 1>(v);
    rev_inreg<7>(v);  stages<2, 1>(v);
    rev_inreg<15>(v); stages<4, 1>(v);
    rev_inreg<31>(v); stages<8, 1>(v);
    rev_inreg<63>(v); stages<16, 1>(v);
    rev_shfl<1>(v, hi1);
    stages<32, 1>(v);
    rev_shfl<3>(v, hi2);
    stage_shfl<2>(v, hi2);
    stage_shfl<1>(v, hi1);
    stages<32, 1>(v);

    // ---- merges 512..4096: 9 LDS rounds, pipelined over one shared buffer.
    // Slot s: buffer owned by wave (s&1); the other wave runs its in-reg
    // stages of the previous round. One barrier per slot boundary.

    // round 1 (m512 rev): write_AB + read_rev_B<15,7,4>; stages<8,4>
    if (wave == 0) { write_AB(buf, v, sAB, t15); read_rev_B<15, 7, 4>(buf, v, t, t15, false); }
    __syncthreads();
    if (wave == 0) { stages<8, 4>(v); }
    else           { write_AB(buf, v, sAB, t15); read_rev_B<15, 7, 4>(buf, v, t, t15, false); }
    __syncthreads();
    // round 2 (m512 tail): write_AB + read_own; stages<32,1>
    if (wave == 0) { write_AB(buf, v, sAB, t15); read_own(buf, v, t, t15); }
    else           { stages<8, 4>(v); }
    __syncthreads();
    if (wave == 0) { stages<32, 1>(v); }
    else           { write_AB(buf, v, sAB, t15); read_own(buf, v, t, t15); }
    __syncthreads();
    // round 3 (m1024 rev): write_AB + read_rev_B<15,15,8>; stages<16,4>
    if (wave == 0) { write_AB(buf, v, sAB, t15); read_rev_B<15, 15, 8>(buf, v, t, t15, false); }
    else           { stages<32, 1>(v); }
    __syncthreads();
    if (wave == 0) { stages<16, 4>(v); }
    else           { write_AB(buf, v, sAB, t15); read_rev_B<15, 15, 8>(buf, v, t, t15, false); }
    __syncthreads();
    // round 4 (m1024 tail): write_AB + read_own; stages<32,1>
    if (wave == 0) { write_AB(buf, v, sAB, t15); read_own(buf, v, t, t15); }
    else           { stages<16, 4>(v); }
    __syncthreads();
    if (wave == 0) { stages<32, 1>(v); }
    else           { write_AB(buf, v, sAB, t15); read_own(buf, v, t, t15); }
    __syncthreads();
    // round 5 (m2048 rev): write_AB + read_rev_B<31,15,0>(hi16); stages<32,4>
    if (wave == 0) { write_AB(buf, v, sAB, t15); read_rev_B<31, 15, 0>(buf, v, t, t15, hi16); }
    else           { stages<32, 1>(v); }
    __syncthreads();
    if (wave == 0) { stages<32, 4>(v); }
    else           { write_AB(buf, v, sAB, t15); read_rev_B<31, 15, 0>(buf, v, t, t15, hi16); }
    __syncthreads();
    // round 6 (m2048 tail): write_AB + read_own; stages<32,1>
    if (wave == 0) { write_AB(buf, v, sAB, t15); read_own(buf, v, t, t15); }
    else           { stages<32, 4>(v); }
    __syncthreads();
    if (wave == 0) { stages<32, 1>(v); }
    else           { write_AB(buf, v, sAB, t15); read_own(buf, v, t, t15); }
    __syncthreads();
    // round 7 (m4096 rev): write_AC + read_rev_C; stages<16,16> (j=1024 in C)
    if (wave == 0) { write_AC(buf, v, t15, qAC); read_rev_C(buf, v, t, th); }
    else           { stages<32, 1>(v); }
    __syncthreads();
    if (wave == 0) { stages<16, 16>(v); }
    else           { write_AC(buf, v, t15, qAC); read_rev_C(buf, v, t, th); }
    __syncthreads();
    // round 8 (m4096 mid): write_CB + read_own; stages<32,4> (j=512..64)
    if (wave == 0) { write_CB(buf, v, sCB, qCB); read_own(buf, v, t, t15); }
    else           { stages<16, 16>(v); }
    __syncthreads();
    if (wave == 0) { stages<32, 4>(v); }
    else           { write_CB(buf, v, sCB, qCB); read_own(buf, v, t, t15); }
    __syncthreads();
    // round 9 (m4096 tail): write_AB + read_own; stages<32,1>
    if (wave == 0) { write_AB(buf, v, sAB, t15); read_own(buf, v, t, t15); }
    else           { stages<32, 4>(v); }
    __syncthreads();
    if (wave == 0) { stages<32, 1>(v); }
    else           { write_AB(buf, v, sAB, t15); read_own(buf, v, t, t15); }
    __syncthreads();
    // tail slot: wave 1 finishes its last stages and publishes sorted y
    if (wave == 1) { stages<32, 1>(v); write_own(buf, v, t, t15); }
    __syncthreads();

    if (wave == 0) {
        float w[V];
        read_own(buf, w, t, t15);
        float s = 0.0f;
#pragma unroll
        for (int r = 0; r < V; ++r) {
            const float d = v[r] - w[r];
            s += d * d;
        }
        for (int off = 32; off > 0; off >>= 1) s += __shfl_down(s, off, 64);
        if (t == 0) atomicAdd(&per_batch[b], s);
    }
}

__global__ void finalize_kernel(const float* __restrict__ per_batch, float* __restrict__ out) {
    const int t = threadIdx.x;  // 64 threads
    float v = (t < NBATCH) ? sqrtf(per_batch[t] * (1.0f / (float)NPROJ)) : 0.0f;
    for (int off = 32; off > 0; off >>= 1) v += __shfl_down(v, off, 64);
    if (t == 0) out[0] = v * (1.0f / (float)NBATCH);
}

extern "C" void kernel_launch(void* const* d_in, const int* in_sizes, int n_in,
                              void* d_out, int out_size, void* d_ws, size_t ws_size,
                              hipStream_t stream) {
    const float* x = (const float*)d_in[0];
    const float* y = (const float*)d_in[1];
    const float* theta = (const float*)d_in[2];
    const float* rot = (const float*)d_in[3];
    float* per_batch = (float*)d_ws;
    float* out = (float*)d_out;

    hipMemsetAsync(per_batch, 0, NBATCH * sizeof(float), stream);

    dim3 grid(NPROJ, NBATCH);
    swd_kernel<<<grid, BLK, 0, stream>>>(x, y, theta, rot, per_batch);

    finalize_kernel<<<1, 64, 0, stream>>>(per_batch, out);
}

// Round 3
// 501.843 us; speedup vs baseline: 1.9929x; 1.9929x over previous
//
#include <hip/hip_runtime.h>
#include <math.h>

#define NPTS 4096
#define BLK 128
#define V 64
#define NPROJ 256
#define NBATCH 32

// R10 (resubmit — R2 bench was an infra failure, container never acquired):
// R9's single shared 16 KiB buffer + two-wave software pipeline, with
// __launch_bounds__(128, 4) instead of (128, 5).
// R9 post-mortem: the (128,5) VGPR cap (512/5 ~= 102) made the allocator
// spill v[64] wholesale (VGPR_Count 48, 4.9 GB scratch traffic/dispatch,
// hbm 63% of peak, VALUBusy 23%). The occupancy mechanism itself worked
// (LDS 16 KiB -> Occupancy 49%). Cap 128 fits the ~100-reg pressure without
// spilling; HW occupancy at VGPR<=128 is 16 waves/CU anyway, so nothing is
// lost vs (128,5).
// Pipeline: buffer ownership alternates per "slot"; while wave 0 runs its
// LDS round k, wave 1 runs its in-register stages of round k-1, and vice
// versa; one __syncthreads per slot. Intra-wave write->read ordering within
// a round is lgkmcnt (no barrier), exactly as the verified R8 kernel.
// Sort network and all layouts unchanged:
// Layouts (element idx, 12 bits; T=wave-lane 6b, c=chunk 4b, l=comp 2b):
//   A: T=idx[11:6], c=idx[5:2]                (regs = idx[5:0])
//   B: T={idx[11:10],idx[5:2]}, c=idx[9:6]    (regs = {idx[9:6],idx[1:0]})
//   C: T=idx[9:4],  c={idx[11:10],idx[3:2]}   (regs = {idx[11:10],idx[3:0]})
// float4-slot placement: A/B: slot=(T<<4)|(c^(T&15)); C: slot=(T<<4)|(c^(T>>2&15)).
// All patterns bank-even (8 dwords/bank per b128) and bijective (verified).
// Normalized bitonic: merges 2..64 in-reg; m128/m256 via shfl_xor (DPP);
// m512..m4096 via LDS with reversal fused into the layout-entry read.
// Wave 1 publishes sorted y into the SAME buffer at the end; wave 0 diffs.

__device__ __forceinline__ void cmpex_asc(float& a, float& b) {
    const float lo = fminf(a, b), hi = fmaxf(a, b);
    a = lo; b = hi;
}

template<int JB, int JL>
__device__ __forceinline__ void stages(float* v) {
#pragma unroll
    for (int r = 0; r < V; ++r)
        if ((r & JB) == 0) cmpex_asc(v[r], v[r | JB]);
    if constexpr (JB > JL) stages<(JB >> 1), JL>(v);
}

template<int MASK>
__device__ __forceinline__ void rev_inreg(float* v) {
    constexpr int S = (MASK + 1) >> 1;
#pragma unroll
    for (int r = 0; r < V; ++r) {
        if ((r & S) == 0) {
            const float a = v[r], b = v[r ^ MASK];
            v[r] = fminf(a, b);
            v[r ^ MASK] = fmaxf(a, b);
        }
    }
}

// Reversal across thread-pair (xor XM), registers reversed (r <-> 63-r).
template<int XM>
__device__ __forceinline__ void rev_shfl(float* v, bool hi) {
#pragma unroll
    for (int r = 0; r < 32; ++r) {
        const float pa = __shfl_xor(v[63 - r], XM, 64);
        const float pb = __shfl_xor(v[r], XM, 64);
        v[r]      = hi ? fmaxf(v[r], pa)      : fminf(v[r], pa);
        v[63 - r] = hi ? fmaxf(v[63 - r], pb) : fminf(v[63 - r], pb);
    }
}
// Same-register cross-thread stage (xor XM).
template<int XM>
__device__ __forceinline__ void stage_shfl(float* v, bool hi) {
#pragma unroll
    for (int r = 0; r < V; ++r) {
        const float q = __shfl_xor(v[r], XM, 64);
        v[r] = hi ? fmaxf(v[r], q) : fminf(v[r], q);
    }
}

// A->B and B->A scatter-write (same formula, symmetric).
__device__ __forceinline__ void write_AB(float* s, const float* v, int sAB, int t15) {
    float4* s4 = (float4*)s;
#pragma unroll
    for (int c = 0; c < 16; ++c)
        s4[sAB | (c << 4) | (t15 ^ c)] =
            make_float4(v[4*c], v[4*c+1], v[4*c+2], v[4*c+3]);
}
// Natural (own-slot) write, A/B-resident layout.
__device__ __forceinline__ void write_own(float* s, const float* v, int t, int t15) {
    float4* s4 = (float4*)s;
#pragma unroll
    for (int c = 0; c < 16; ++c)
        s4[(t << 4) | (c ^ t15)] =
            make_float4(v[4*c], v[4*c+1], v[4*c+2], v[4*c+3]);
}
// Own-slot read, valid for A- and B-resident phases.
__device__ __forceinline__ void read_own(const float* s, float* v, int t, int t15) {
    const float4* s4 = (const float4*)s;
#pragma unroll
    for (int c = 0; c < 16; ++c) {
        const float4 f = s4[(t << 4) | (c ^ t15)];
        v[4*c] = f.x; v[4*c+1] = f.y; v[4*c+2] = f.z; v[4*c+3] = f.w;
    }
}
// B-entry read fused with reversal: own + partner (t^PM, c^CM, comps
// reversed). Keep side: chunk bit KB, or thread-uniform thi when KB==0.
template<int PM, int CM, int KB>
__device__ __forceinline__ void read_rev_B(const float* s, float* v, int t, int t15, bool thi) {
    const float4* s4 = (const float4*)s;
    const int pt = t ^ PM, pt15 = t15 ^ (PM & 15);
#pragma unroll
    for (int c = 0; c < 16; ++c) {
        const float4 o = s4[(t << 4) | (c ^ t15)];
        const float4 q = s4[(pt << 4) | ((c ^ CM) ^ pt15)];
        const bool mx = KB ? ((c & KB) != 0) : thi;
        v[4*c+0] = mx ? fmaxf(o.x, q.w) : fminf(o.x, q.w);
        v[4*c+1] = mx ? fmaxf(o.y, q.z) : fminf(o.y, q.z);
        v[4*c+2] = mx ? fmaxf(o.z, q.y) : fminf(o.z, q.y);
        v[4*c+3] = mx ? fmaxf(o.w, q.x) : fminf(o.w, q.x);
    }
}
// A->C scatter-write.
__device__ __forceinline__ void write_AC(float* s, const float* v, int t15, int qAC) {
    float4* s4 = (float4*)s;
#pragma unroll
    for (int c = 0; c < 16; ++c)
        s4[(t15 << 6) | ((c >> 2) << 4) | (qAC ^ (c & 3))] =
            make_float4(v[4*c], v[4*c+1], v[4*c+2], v[4*c+3]);
}
// C-entry read fused with m4096 reversal (partner t^63, c^15, keep c&8).
__device__ __forceinline__ void read_rev_C(const float* s, float* v, int t, int th) {
    const float4* s4 = (const float4*)s;
    const int pt = t ^ 63, pth = th ^ 15;
#pragma unroll
    for (int c = 0; c < 16; ++c) {
        const float4 o = s4[(t << 4) | (c ^ th)];
        const float4 q = s4[(pt << 4) | ((c ^ 15) ^ pth)];
        const bool mx = (c & 8) != 0;
        v[4*c+0] = mx ? fmaxf(o.x, q.w) : fminf(o.x, q.w);
        v[4*c+1] = mx ? fmaxf(o.y, q.z) : fminf(o.y, q.z);
        v[4*c+2] = mx ? fmaxf(o.z, q.y) : fminf(o.z, q.y);
        v[4*c+3] = mx ? fmaxf(o.w, q.x) : fminf(o.w, q.x);
    }
}
// C->B scatter-write.
__device__ __forceinline__ void write_CB(float* s, const float* v, int sCB, int qCB) {
    float4* s4 = (float4*)s;
#pragma unroll
    for (int c = 0; c < 16; ++c)
        s4[((c >> 2) << 8) | sCB | ((c & 3) << 4) | (qCB ^ (c & 3))] =
            make_float4(v[4*c], v[4*c+1], v[4*c+2], v[4*c+3]);
}

__device__ __forceinline__ void load_project(const float* base, float* v,
                                             float p0, float p1, float p2) {
    const float4* b4 = (const float4*)base;
#pragma unroll
    for (int g = 0; g < 16; ++g) {
        float4 a = b4[g * 3 + 0], c = b4[g * 3 + 1], d = b4[g * 3 + 2];
        v[4*g+0] = a.x * p0 + a.y * p1 + a.z * p2;
        v[4*g+1] = a.w * p0 + c.x * p1 + c.y * p2;
        v[4*g+2] = c.z * p0 + c.w * p1 + d.x * p2;
        v[4*g+3] = d.y * p0 + d.z * p1 + d.w * p2;
    }
}

__global__ __launch_bounds__(BLK, 4) void swd_kernel(
    const float* __restrict__ x, const float* __restrict__ y,
    const float* __restrict__ theta, const float* __restrict__ rot,
    float* __restrict__ per_batch) {
    __shared__ float buf[NPTS];   // 16 KiB — shared between the two waves

    const int t = threadIdx.x & 63;       // wave lane
    const int wave = threadIdx.x >> 6;    // 0: x, 1: y
    const int p = blockIdx.x;
    const int b = blockIdx.y;

    const float t0 = theta[p * 3 + 0], t1 = theta[p * 3 + 1], t2 = theta[p * 3 + 2];
    const float* R = rot + b * 9;
    const float p0 = t0 * R[0] + t1 * R[3] + t2 * R[6];
    const float p1 = t0 * R[1] + t1 * R[4] + t2 * R[7];
    const float p2 = t0 * R[2] + t1 * R[5] + t2 * R[8];

    const float* src = wave ? y : x;

    float v[V];
    load_project(src + (size_t)b * NPTS * 3 + (size_t)t * V * 3, v, p0, p1, p2);

    const int t15 = t & 15;
    const int sAB = (t >> 4) << 8;
    const int qAC = ((t >> 4) << 2) ^ t15;
    const int th  = (t >> 2) & 15;
    const int sCB = (t & 3) << 6;
    const int qCB = (t >> 2) ^ ((t & 3) << 2);
    const bool hi1  = (t & 1) != 0;
    const bool hi2  = (t & 2) != 0;
    const bool hi16 = (t & 16) != 0;

    // ---- merges 2..256: fully in-register / DPP, both waves concurrently
    rev_inreg<1>(v);
    rev_inreg<3>(v);  stages<1, 1>(v);
    rev_inreg<7>(v);  stages<2, 1>(v);
    rev_inreg<15>(v); stages<4, 1>(v);
    rev_inreg<31>(v); stages<8, 1>(v);
    rev_inreg<63>(v); stages<16, 1>(v);
    rev_shfl<1>(v, hi1);
    stages<32, 1>(v);
    rev_shfl<3>(v, hi2);
    stage_shfl<2>(v, hi2);
    stage_shfl<1>(v, hi1);
    stages<32, 1>(v);

    // ---- merges 512..4096: 9 LDS rounds, pipelined over one shared buffer.
    // Slot s: buffer owned by wave (s&1); the other wave runs its in-reg
    // stages of the previous round. One barrier per slot boundary.

    // round 1 (m512 rev): write_AB + read_rev_B<15,7,4>; stages<8,4>
    if (wave == 0) { write_AB(buf, v, sAB, t15); read_rev_B<15, 7, 4>(buf, v, t, t15, false); }
    __syncthreads();
    if (wave == 0) { stages<8, 4>(v); }
    else           { write_AB(buf, v, sAB, t15); read_rev_B<15, 7, 4>(buf, v, t, t15, false); }
    __syncthreads();
    // round 2 (m512 tail): write_AB + read_own; stages<32,1>
    if (wave == 0) { write_AB(buf, v, sAB, t15); read_own(buf, v, t, t15); }
    else           { stages<8, 4>(v); }
    __syncthreads();
    if (wave == 0) { stages<32, 1>(v); }
    else           { write_AB(buf, v, sAB, t15); read_own(buf, v, t, t15); }
    __syncthreads();
    // round 3 (m1024 rev): write_AB + read_rev_B<15,15,8>; stages<16,4>
    if (wave == 0) { write_AB(buf, v, sAB, t15); read_rev_B<15, 15, 8>(buf, v, t, t15, false); }
    else           { stages<32, 1>(v); }
    __syncthreads();
    if (wave == 0) { stages<16, 4>(v); }
    else           { write_AB(buf, v, sAB, t15); read_rev_B<15, 15, 8>(buf, v, t, t15, false); }
    __syncthreads();
    // round 4 (m1024 tail): write_AB + read_own; stages<32,1>
    if (wave == 0) { write_AB(buf, v, sAB, t15); read_own(buf, v, t, t15); }
    else           { stages<16, 4>(v); }
    __syncthreads();
    if (wave == 0) { stages<32, 1>(v); }
    else           { write_AB(buf, v, sAB, t15); read_own(buf, v, t, t15); }
    __syncthreads();
    // round 5 (m2048 rev): write_AB + read_rev_B<31,15,0>(hi16); stages<32,4>
    if (wave == 0) { write_AB(buf, v, sAB, t15); read_rev_B<31, 15, 0>(buf, v, t, t15, hi16); }
    else           { stages<32, 1>(v); }
    __syncthreads();
    if (wave == 0) { stages<32, 4>(v); }
    else           { write_AB(buf, v, sAB, t15); read_rev_B<31, 15, 0>(buf, v, t, t15, hi16); }
    __syncthreads();
    // round 6 (m2048 tail): write_AB + read_own; stages<32,1>
    if (wave == 0) { write_AB(buf, v, sAB, t15); read_own(buf, v, t, t15); }
    else           { stages<32, 4>(v); }
    __syncthreads();
    if (wave == 0) { stages<32, 1>(v); }
    else           { write_AB(buf, v, sAB, t15); read_own(buf, v, t, t15); }
    __syncthreads();
    // round 7 (m4096 rev): write_AC + read_rev_C; stages<16,16> (j=1024 in C)
    if (wave == 0) { write_AC(buf, v, t15, qAC); read_rev_C(buf, v, t, th); }
    else           { stages<32, 1>(v); }
    __syncthreads();
    if (wave == 0) { stages<16, 16>(v); }
    else           { write_AC(buf, v, t15, qAC); read_rev_C(buf, v, t, th); }
    __syncthreads();
    // round 8 (m4096 mid): write_CB + read_own; stages<32,4> (j=512..64)
    if (wave == 0) { write_CB(buf, v, sCB, qCB); read_own(buf, v, t, t15); }
    else           { stages<16, 16>(v); }
    __syncthreads();
    if (wave == 0) { stages<32, 4>(v); }
    else           { write_CB(buf, v, sCB, qCB); read_own(buf, v, t, t15); }
    __syncthreads();
    // round 9 (m4096 tail): write_AB + read_own; stages<32,1>
    if (wave == 0) { write_AB(buf, v, sAB, t15); read_own(buf, v, t, t15); }
    else           { stages<32, 4>(v); }
    __syncthreads();
    if (wave == 0) { stages<32, 1>(v); }
    else           { write_AB(buf, v, sAB, t15); read_own(buf, v, t, t15); }
    __syncthreads();
    // tail slot: wave 1 finishes its last stages and publishes sorted y
    if (wave == 1) { stages<32, 1>(v); write_own(buf, v, t, t15); }
    __syncthreads();

    if (wave == 0) {
        float w[V];
        read_own(buf, w, t, t15);
        float s = 0.0f;
#pragma unroll
        for (int r = 0; r < V; ++r) {
            const float d = v[r] - w[r];
            s += d * d;
        }
        for (int off = 32; off > 0; off >>= 1) s += __shfl_down(s, off, 64);
        if (t == 0) atomicAdd(&per_batch[b], s);
    }
}

__global__ void finalize_kernel(const float* __restrict__ per_batch, float* __restrict__ out) {
    const int t = threadIdx.x;  // 64 threads
    float v = (t < NBATCH) ? sqrtf(per_batch[t] * (1.0f / (float)NPROJ)) : 0.0f;
    for (int off = 32; off > 0; off >>= 1) v += __shfl_down(v, off, 64);
    if (t == 0) out[0] = v * (1.0f / (float)NBATCH);
}

extern "C" void kernel_launch(void* const* d_in, const int* in_sizes, int n_in,
                              void* d_out, int out_size, void* d_ws, size_t ws_size,
                              hipStream_t stream) {
    const float* x = (const float*)d_in[0];
    const float* y = (const float*)d_in[1];
    const float* theta = (const float*)d_in[2];
    const float* rot = (const float*)d_in[3];
    float* per_batch = (float*)d_ws;
    float* out = (float*)d_out;

    hipMemsetAsync(per_batch, 0, NBATCH * sizeof(float), stream);

    dim3 grid(NPROJ, NBATCH);
    swd_kernel<<<grid, BLK, 0, stream>>>(x, y, theta, rot, per_batch);

    finalize_kernel<<<1, 64, 0, stream>>>(per_batch, out);
}

// Round 4
// 381.641 us; speedup vs baseline: 2.6205x; 1.3150x over previous
//
#include <hip/hip_runtime.h>
#include <math.h>

#define NPTS 4096
#define BLK 128
#define V 64
#define NPROJ 256
#define NBATCH 32

// R11: R9/R10's single shared 16 KiB buffer + two-wave software pipeline,
// with __launch_bounds__(128, 2) (VGPR cap 256 — same relaxed bound as the
// verified 84-reg R8 kernel).
// R9 (cap~102) and R10 (cap 128) both made the allocator spill v[64]
// wholesale (VGPR_Count 48/64, 0.9-4.9 GB scratch traffic/dispatch): the
// if/else pipeline keeps both branch bodies in the scheduling window so
// peak pressure exceeds 128. Cap 256 lets it allocate cleanly.
// Occupancy evidence from R8/R10: effective LDS pool ~112 KiB/CU (both
// rounds landed at ~107 KiB aggregate); 16 KiB/block -> ~7 blocks = 14
// waves/CU (42% measured in R10) vs R8's 6.7 waves at 32 KiB. The pipeline
// adds no per-wave work vs R8, so 2x waves should saturate VALU issue.
// Pipeline: buffer ownership alternates per "slot"; while wave 0 runs its
// LDS round k, wave 1 runs its in-register stages of round k-1, and vice
// versa; one __syncthreads per slot. Intra-wave write->read ordering within
// a round is lgkmcnt (no barrier), exactly as the verified R8 kernel.
// Sort network and all layouts unchanged:
// Layouts (element idx, 12 bits; T=wave-lane 6b, c=chunk 4b, l=comp 2b):
//   A: T=idx[11:6], c=idx[5:2]                (regs = idx[5:0])
//   B: T={idx[11:10],idx[5:2]}, c=idx[9:6]    (regs = {idx[9:6],idx[1:0]})
//   C: T=idx[9:4],  c={idx[11:10],idx[3:2]}   (regs = {idx[11:10],idx[3:0]})
// float4-slot placement: A/B: slot=(T<<4)|(c^(T&15)); C: slot=(T<<4)|(c^(T>>2&15)).
// All patterns bank-even (8 dwords/bank per b128) and bijective (verified).
// Normalized bitonic: merges 2..64 in-reg; m128/m256 via shfl_xor (DPP);
// m512..m4096 via LDS with reversal fused into the layout-entry read.
// Wave 1 publishes sorted y into the SAME buffer at the end; wave 0 diffs.

__device__ __forceinline__ void cmpex_asc(float& a, float& b) {
    const float lo = fminf(a, b), hi = fmaxf(a, b);
    a = lo; b = hi;
}

template<int JB, int JL>
__device__ __forceinline__ void stages(float* v) {
#pragma unroll
    for (int r = 0; r < V; ++r)
        if ((r & JB) == 0) cmpex_asc(v[r], v[r | JB]);
    if constexpr (JB > JL) stages<(JB >> 1), JL>(v);
}

template<int MASK>
__device__ __forceinline__ void rev_inreg(float* v) {
    constexpr int S = (MASK + 1) >> 1;
#pragma unroll
    for (int r = 0; r < V; ++r) {
        if ((r & S) == 0) {
            const float a = v[r], b = v[r ^ MASK];
            v[r] = fminf(a, b);
            v[r ^ MASK] = fmaxf(a, b);
        }
    }
}

// Reversal across thread-pair (xor XM), registers reversed (r <-> 63-r).
template<int XM>
__device__ __forceinline__ void rev_shfl(float* v, bool hi) {
#pragma unroll
    for (int r = 0; r < 32; ++r) {
        const float pa = __shfl_xor(v[63 - r], XM, 64);
        const float pb = __shfl_xor(v[r], XM, 64);
        v[r]      = hi ? fmaxf(v[r], pa)      : fminf(v[r], pa);
        v[63 - r] = hi ? fmaxf(v[63 - r], pb) : fminf(v[63 - r], pb);
    }
}
// Same-register cross-thread stage (xor XM).
template<int XM>
__device__ __forceinline__ void stage_shfl(float* v, bool hi) {
#pragma unroll
    for (int r = 0; r < V; ++r) {
        const float q = __shfl_xor(v[r], XM, 64);
        v[r] = hi ? fmaxf(v[r], q) : fminf(v[r], q);
    }
}

// A->B and B->A scatter-write (same formula, symmetric).
__device__ __forceinline__ void write_AB(float* s, const float* v, int sAB, int t15) {
    float4* s4 = (float4*)s;
#pragma unroll
    for (int c = 0; c < 16; ++c)
        s4[sAB | (c << 4) | (t15 ^ c)] =
            make_float4(v[4*c], v[4*c+1], v[4*c+2], v[4*c+3]);
}
// Natural (own-slot) write, A/B-resident layout.
__device__ __forceinline__ void write_own(float* s, const float* v, int t, int t15) {
    float4* s4 = (float4*)s;
#pragma unroll
    for (int c = 0; c < 16; ++c)
        s4[(t << 4) | (c ^ t15)] =
            make_float4(v[4*c], v[4*c+1], v[4*c+2], v[4*c+3]);
}
// Own-slot read, valid for A- and B-resident phases.
__device__ __forceinline__ void read_own(const float* s, float* v, int t, int t15) {
    const float4* s4 = (const float4*)s;
#pragma unroll
    for (int c = 0; c < 16; ++c) {
        const float4 f = s4[(t << 4) | (c ^ t15)];
        v[4*c] = f.x; v[4*c+1] = f.y; v[4*c+2] = f.z; v[4*c+3] = f.w;
    }
}
// B-entry read fused with reversal: own + partner (t^PM, c^CM, comps
// reversed). Keep side: chunk bit KB, or thread-uniform thi when KB==0.
template<int PM, int CM, int KB>
__device__ __forceinline__ void read_rev_B(const float* s, float* v, int t, int t15, bool thi) {
    const float4* s4 = (const float4*)s;
    const int pt = t ^ PM, pt15 = t15 ^ (PM & 15);
#pragma unroll
    for (int c = 0; c < 16; ++c) {
        const float4 o = s4[(t << 4) | (c ^ t15)];
        const float4 q = s4[(pt << 4) | ((c ^ CM) ^ pt15)];
        const bool mx = KB ? ((c & KB) != 0) : thi;
        v[4*c+0] = mx ? fmaxf(o.x, q.w) : fminf(o.x, q.w);
        v[4*c+1] = mx ? fmaxf(o.y, q.z) : fminf(o.y, q.z);
        v[4*c+2] = mx ? fmaxf(o.z, q.y) : fminf(o.z, q.y);
        v[4*c+3] = mx ? fmaxf(o.w, q.x) : fminf(o.w, q.x);
    }
}
// A->C scatter-write.
__device__ __forceinline__ void write_AC(float* s, const float* v, int t15, int qAC) {
    float4* s4 = (float4*)s;
#pragma unroll
    for (int c = 0; c < 16; ++c)
        s4[(t15 << 6) | ((c >> 2) << 4) | (qAC ^ (c & 3))] =
            make_float4(v[4*c], v[4*c+1], v[4*c+2], v[4*c+3]);
}
// C-entry read fused with m4096 reversal (partner t^63, c^15, keep c&8).
__device__ __forceinline__ void read_rev_C(const float* s, float* v, int t, int th) {
    const float4* s4 = (const float4*)s;
    const int pt = t ^ 63, pth = th ^ 15;
#pragma unroll
    for (int c = 0; c < 16; ++c) {
        const float4 o = s4[(t << 4) | (c ^ th)];
        const float4 q = s4[(pt << 4) | ((c ^ 15) ^ pth)];
        const bool mx = (c & 8) != 0;
        v[4*c+0] = mx ? fmaxf(o.x, q.w) : fminf(o.x, q.w);
        v[4*c+1] = mx ? fmaxf(o.y, q.z) : fminf(o.y, q.z);
        v[4*c+2] = mx ? fmaxf(o.z, q.y) : fminf(o.z, q.y);
        v[4*c+3] = mx ? fmaxf(o.w, q.x) : fminf(o.w, q.x);
    }
}
// C->B scatter-write.
__device__ __forceinline__ void write_CB(float* s, const float* v, int sCB, int qCB) {
    float4* s4 = (float4*)s;
#pragma unroll
    for (int c = 0; c < 16; ++c)
        s4[((c >> 2) << 8) | sCB | ((c & 3) << 4) | (qCB ^ (c & 3))] =
            make_float4(v[4*c], v[4*c+1], v[4*c+2], v[4*c+3]);
}

__device__ __forceinline__ void load_project(const float* base, float* v,
                                             float p0, float p1, float p2) {
    const float4* b4 = (const float4*)base;
#pragma unroll
    for (int g = 0; g < 16; ++g) {
        float4 a = b4[g * 3 + 0], c = b4[g * 3 + 1], d = b4[g * 3 + 2];
        v[4*g+0] = a.x * p0 + a.y * p1 + a.z * p2;
        v[4*g+1] = a.w * p0 + c.x * p1 + c.y * p2;
        v[4*g+2] = c.z * p0 + c.w * p1 + d.x * p2;
        v[4*g+3] = d.y * p0 + d.z * p1 + d.w * p2;
    }
}

__global__ __launch_bounds__(BLK, 2) void swd_kernel(
    const float* __restrict__ x, const float* __restrict__ y,
    const float* __restrict__ theta, const float* __restrict__ rot,
    float* __restrict__ per_batch) {
    __shared__ float buf[NPTS];   // 16 KiB — shared between the two waves

    const int t = threadIdx.x & 63;       // wave lane
    const int wave = threadIdx.x >> 6;    // 0: x, 1: y
    const int p = blockIdx.x;
    const int b = blockIdx.y;

    const float t0 = theta[p * 3 + 0], t1 = theta[p * 3 + 1], t2 = theta[p * 3 + 2];
    const float* R = rot + b * 9;
    const float p0 = t0 * R[0] + t1 * R[3] + t2 * R[6];
    const float p1 = t0 * R[1] + t1 * R[4] + t2 * R[7];
    const float p2 = t0 * R[2] + t1 * R[5] + t2 * R[8];

    const float* src = wave ? y : x;

    float v[V];
    load_project(src + (size_t)b * NPTS * 3 + (size_t)t * V * 3, v, p0, p1, p2);

    const int t15 = t & 15;
    const int sAB = (t >> 4) << 8;
    const int qAC = ((t >> 4) << 2) ^ t15;
    const int th  = (t >> 2) & 15;
    const int sCB = (t & 3) << 6;
    const int qCB = (t >> 2) ^ ((t & 3) << 2);
    const bool hi1  = (t & 1) != 0;
    const bool hi2  = (t & 2) != 0;
    const bool hi16 = (t & 16) != 0;

    // ---- merges 2..256: fully in-register / DPP, both waves concurrently
    rev_inreg<1>(v);
    rev_inreg<3>(v);  stages<1, 1>(v);
    rev_inreg<7>(v);  stages<2, 1>(v);
    rev_inreg<15>(v); stages<4, 1>(v);
    rev_inreg<31>(v); stages<8, 1>(v);
    rev_inreg<63>(v); stages<16, 1>(v);
    rev_shfl<1>(v, hi1);
    stages<32, 1>(v);
    rev_shfl<3>(v, hi2);
    stage_shfl<2>(v, hi2);
    stage_shfl<1>(v, hi1);
    stages<32, 1>(v);

    // ---- merges 512..4096: 9 LDS rounds, pipelined over one shared buffer.
    // Slot s: buffer owned by wave (s&1); the other wave runs its in-reg
    // stages of the previous round. One barrier per slot boundary.

    // round 1 (m512 rev): write_AB + read_rev_B<15,7,4>; stages<8,4>
    if (wave == 0) { write_AB(buf, v, sAB, t15); read_rev_B<15, 7, 4>(buf, v, t, t15, false); }
    __syncthreads();
    if (wave == 0) { stages<8, 4>(v); }
    else           { write_AB(buf, v, sAB, t15); read_rev_B<15, 7, 4>(buf, v, t, t15, false); }
    __syncthreads();
    // round 2 (m512 tail): write_AB + read_own; stages<32,1>
    if (wave == 0) { write_AB(buf, v, sAB, t15); read_own(buf, v, t, t15); }
    else           { stages<8, 4>(v); }
    __syncthreads();
    if (wave == 0) { stages<32, 1>(v); }
    else           { write_AB(buf, v, sAB, t15); read_own(buf, v, t, t15); }
    __syncthreads();
    // round 3 (m1024 rev): write_AB + read_rev_B<15,15,8>; stages<16,4>
    if (wave == 0) { write_AB(buf, v, sAB, t15); read_rev_B<15, 15, 8>(buf, v, t, t15, false); }
    else           { stages<32, 1>(v); }
    __syncthreads();
    if (wave == 0) { stages<16, 4>(v); }
    else           { write_AB(buf, v, sAB, t15); read_rev_B<15, 15, 8>(buf, v, t, t15, false); }
    __syncthreads();
    // round 4 (m1024 tail): write_AB + read_own; stages<32,1>
    if (wave == 0) { write_AB(buf, v, sAB, t15); read_own(buf, v, t, t15); }
    else           { stages<16, 4>(v); }
    __syncthreads();
    if (wave == 0) { stages<32, 1>(v); }
    else           { write_AB(buf, v, sAB, t15); read_own(buf, v, t, t15); }
    __syncthreads();
    // round 5 (m2048 rev): write_AB + read_rev_B<31,15,0>(hi16); stages<32,4>
    if (wave == 0) { write_AB(buf, v, sAB, t15); read_rev_B<31, 15, 0>(buf, v, t, t15, hi16); }
    else           { stages<32, 1>(v); }
    __syncthreads();
    if (wave == 0) { stages<32, 4>(v); }
    else           { write_AB(buf, v, sAB, t15); read_rev_B<31, 15, 0>(buf, v, t, t15, hi16); }
    __syncthreads();
    // round 6 (m2048 tail): write_AB + read_own; stages<32,1>
    if (wave == 0) { write_AB(buf, v, sAB, t15); read_own(buf, v, t, t15); }
    else           { stages<32, 4>(v); }
    __syncthreads();
    if (wave == 0) { stages<32, 1>(v); }
    else           { write_AB(buf, v, sAB, t15); read_own(buf, v, t, t15); }
    __syncthreads();
    // round 7 (m4096 rev): write_AC + read_rev_C; stages<16,16> (j=1024 in C)
    if (wave == 0) { write_AC(buf, v, t15, qAC); read_rev_C(buf, v, t, th); }
    else           { stages<32, 1>(v); }
    __syncthreads();
    if (wave == 0) { stages<16, 16>(v); }
    else           { write_AC(buf, v, t15, qAC); read_rev_C(buf, v, t, th); }
    __syncthreads();
    // round 8 (m4096 mid): write_CB + read_own; stages<32,4> (j=512..64)
    if (wave == 0) { write_CB(buf, v, sCB, qCB); read_own(buf, v, t, t15); }
    else           { stages<16, 16>(v); }
    __syncthreads();
    if (wave == 0) { stages<32, 4>(v); }
    else           { write_CB(buf, v, sCB, qCB); read_own(buf, v, t, t15); }
    __syncthreads();
    // round 9 (m4096 tail): write_AB + read_own; stages<32,1>
    if (wave == 0) { write_AB(buf, v, sAB, t15); read_own(buf, v, t, t15); }
    else           { stages<32, 4>(v); }
    __syncthreads();
    if (wave == 0) { stages<32, 1>(v); }
    else           { write_AB(buf, v, sAB, t15); read_own(buf, v, t, t15); }
    __syncthreads();
    // tail slot: wave 1 finishes its last stages and publishes sorted y
    if (wave == 1) { stages<32, 1>(v); write_own(buf, v, t, t15); }
    __syncthreads();

    if (wave == 0) {
        float w[V];
        read_own(buf, w, t, t15);
        float s = 0.0f;
#pragma unroll
        for (int r = 0; r < V; ++r) {
            const float d = v[r] - w[r];
            s += d * d;
        }
        for (int off = 32; off > 0; off >>= 1) s += __shfl_down(s, off, 64);
        if (t == 0) atomicAdd(&per_batch[b], s);
    }
}

__global__ void finalize_kernel(const float* __restrict__ per_batch, float* __restrict__ out) {
    const int t = threadIdx.x;  // 64 threads
    float v = (t < NBATCH) ? sqrtf(per_batch[t] * (1.0f / (float)NPROJ)) : 0.0f;
    for (int off = 32; off > 0; off >>= 1) v += __shfl_down(v, off, 64);
    if (t == 0) out[0] = v * (1.0f / (float)NBATCH);
}

extern "C" void kernel_launch(void* const* d_in, const int* in_sizes, int n_in,
                              void* d_out, int out_size, void* d_ws, size_t ws_size,
                              hipStream_t stream) {
    const float* x = (const float*)d_in[0];
    const float* y = (const float*)d_in[1];
    const float* theta = (const float*)d_in[2];
    const float* rot = (const float*)d_in[3];
    float* per_batch = (float*)d_ws;
    float* out = (float*)d_out;

    hipMemsetAsync(per_batch, 0, NBATCH * sizeof(float), stream);

    dim3 grid(NPROJ, NBATCH);
    swd_kernel<<<grid, BLK, 0, stream>>>(x, y, theta, rot, per_batch);

    finalize_kernel<<<1, 64, 0, stream>>>(per_batch, out);
}

// Round 5
// 365.077 us; speedup vs baseline: 2.7394x; 1.0454x over previous
//
#include <hip/hip_runtime.h>
#include <math.h>

#define NPTS 4096
#define BLK 128
#define V 64
#define NPROJ 256
#define NBATCH 32

// R12: LDS-free bitonic sort — all cross-element exchanges done by shfl_xor.
// Insight: in layout A (element idx = lane*64 + reg), EVERY exchange of every
// merge size 128..4096 is intra-wave: merge m's reversal is lane t^((m-1)>>6)
// with regs r<->63-r (the rev_shfl primitive already verified for m128/m256),
// and cleaner stages j=128..1024 are lane t^(j>>6) same-reg (stage_shfl).
// This deletes the 9 LDS re-layout rounds of R8 (352 ds_*_b128 ops/wave,
// ~4.2K LDS-unit cycles + full lgkmcnt write->read drains + bank conflicts —
// SQ_LDS_BANK_CONFLICT was clipped at 2^23) and all the A/B/C layout
// machinery. Replacement: ~1400 shfl ops/wave, of which ~768 are DPP-class
// (masks 1,2,3 -> quad_perm, VALU) and ~640 swizzle/bpermute. Zero bank
// conflicts, zero drains, no address arithmetic, no LDS during the sort.
// R11 post-mortem (why not occupancy): measured waves/CU ~ 800/VGPR across
// R8-R11; LDS size was never the binder for non-spilled kernels, and the
// lockstep barrier pipeline cost 18%. So: barrier-free waves (R8 structure),
// data-movement cost attacked instead.
// LDS now = one 16 KiB publish buffer (wave 1's sorted y -> wave 0 diffs).
// Network per merge m (normalized bitonic, rev replaces j=m/2):
//   rev_shfl<(m-1)>>6>(hi = t & (m>>7)); stage_shfl<j>>6>(hi = t&(j>>6))
//   for j=m/4..64; stages<32,1> in-reg. Directions match the verified
//   m128/m256 code pattern exactly.

__device__ __forceinline__ void cmpex_asc(float& a, float& b) {
    const float lo = fminf(a, b), hi = fmaxf(a, b);
    a = lo; b = hi;
}

template<int JB, int JL>
__device__ __forceinline__ void stages(float* v) {
#pragma unroll
    for (int r = 0; r < V; ++r)
        if ((r & JB) == 0) cmpex_asc(v[r], v[r | JB]);
    if constexpr (JB > JL) stages<(JB >> 1), JL>(v);
}

template<int MASK>
__device__ __forceinline__ void rev_inreg(float* v) {
    constexpr int S = (MASK + 1) >> 1;
#pragma unroll
    for (int r = 0; r < V; ++r) {
        if ((r & S) == 0) {
            const float a = v[r], b = v[r ^ MASK];
            v[r] = fminf(a, b);
            v[r ^ MASK] = fmaxf(a, b);
        }
    }
}

// Reversal across thread-pair (xor XM), registers reversed (r <-> 63-r).
// Element (t, r) exchanges with (t^XM, 63-r); hi lanes keep max.
template<int XM>
__device__ __forceinline__ void rev_shfl(float* v, bool hi) {
#pragma unroll
    for (int r = 0; r < 32; ++r) {
        const float pa = __shfl_xor(v[63 - r], XM, 64);
        const float pb = __shfl_xor(v[r], XM, 64);
        v[r]      = hi ? fmaxf(v[r], pa)      : fminf(v[r], pa);
        v[63 - r] = hi ? fmaxf(v[63 - r], pb) : fminf(v[63 - r], pb);
    }
}
// Same-register cross-thread stage (xor XM).
template<int XM>
__device__ __forceinline__ void stage_shfl(float* v, bool hi) {
#pragma unroll
    for (int r = 0; r < V; ++r) {
        const float q = __shfl_xor(v[r], XM, 64);
        v[r] = hi ? fmaxf(v[r], q) : fminf(v[r], q);
    }
}

// Natural (own-slot) publish write/read, float4-slot = (t<<4)|(c^t15)
// (bank-spreading XOR placement, verified in R8).
__device__ __forceinline__ void write_own(float* s, const float* v, int t, int t15) {
    float4* s4 = (float4*)s;
#pragma unroll
    for (int c = 0; c < 16; ++c)
        s4[(t << 4) | (c ^ t15)] =
            make_float4(v[4*c], v[4*c+1], v[4*c+2], v[4*c+3]);
}
__device__ __forceinline__ void read_own(const float* s, float* v, int t, int t15) {
    const float4* s4 = (const float4*)s;
#pragma unroll
    for (int c = 0; c < 16; ++c) {
        const float4 f = s4[(t << 4) | (c ^ t15)];
        v[4*c] = f.x; v[4*c+1] = f.y; v[4*c+2] = f.z; v[4*c+3] = f.w;
    }
}

__device__ __forceinline__ void load_project(const float* base, float* v,
                                             float p0, float p1, float p2) {
    const float4* b4 = (const float4*)base;
#pragma unroll
    for (int g = 0; g < 16; ++g) {
        float4 a = b4[g * 3 + 0], c = b4[g * 3 + 1], d = b4[g * 3 + 2];
        v[4*g+0] = a.x * p0 + a.y * p1 + a.z * p2;
        v[4*g+1] = a.w * p0 + c.x * p1 + c.y * p2;
        v[4*g+2] = c.z * p0 + c.w * p1 + d.x * p2;
        v[4*g+3] = d.y * p0 + d.z * p1 + d.w * p2;
    }
}

// Full ascending sort of 4096 floats held as v[64] per thread, layout A
// (element idx = t*64 + r). Pure in-register + cross-lane; no LDS.
__device__ __forceinline__ void sort4096(float* v, int t) {
    const bool hi1  = (t & 1) != 0;
    const bool hi2  = (t & 2) != 0;
    const bool hi4  = (t & 4) != 0;
    const bool hi8  = (t & 8) != 0;
    const bool hi16 = (t & 16) != 0;
    const bool hi32 = (t & 32) != 0;

    // merges 2..64: fully in-register (verified)
    rev_inreg<1>(v);
    rev_inreg<3>(v);  stages<1, 1>(v);
    rev_inreg<7>(v);  stages<2, 1>(v);
    rev_inreg<15>(v); stages<4, 1>(v);
    rev_inreg<31>(v); stages<8, 1>(v);
    rev_inreg<63>(v); stages<16, 1>(v);

    // merge 128: rev across t^1 (regs reversed), then j=32..1 in-reg (verified)
    rev_shfl<1>(v, hi1);
    stages<32, 1>(v);

    // merge 256: rev t^3; j=128 (t^2), j=64 (t^1); j=32..1 (verified)
    rev_shfl<3>(v, hi2);
    stage_shfl<2>(v, hi2);
    stage_shfl<1>(v, hi1);
    stages<32, 1>(v);

    // merge 512: rev t^7 (idx^511); j=128 (t^2), j=64 (t^1); j=32..1
    rev_shfl<7>(v, hi4);
    stage_shfl<2>(v, hi2);
    stage_shfl<1>(v, hi1);
    stages<32, 1>(v);

    // merge 1024: rev t^15 (idx^1023); j=256 (t^4), 128, 64; j=32..1
    rev_shfl<15>(v, hi8);
    stage_shfl<4>(v, hi4);
    stage_shfl<2>(v, hi2);
    stage_shfl<1>(v, hi1);
    stages<32, 1>(v);

    // merge 2048: rev t^31 (idx^2047); j=512 (t^8), 256, 128, 64; j=32..1
    rev_shfl<31>(v, hi16);
    stage_shfl<8>(v, hi8);
    stage_shfl<4>(v, hi4);
    stage_shfl<2>(v, hi2);
    stage_shfl<1>(v, hi1);
    stages<32, 1>(v);

    // merge 4096: rev t^63 (idx^4095); j=1024 (t^16), 512, 256, 128, 64; j=32..1
    rev_shfl<63>(v, hi32);
    stage_shfl<16>(v, hi16);
    stage_shfl<8>(v, hi8);
    stage_shfl<4>(v, hi4);
    stage_shfl<2>(v, hi2);
    stage_shfl<1>(v, hi1);
    stages<32, 1>(v);
}

__global__ __launch_bounds__(BLK, 2) void swd_kernel(
    const float* __restrict__ x, const float* __restrict__ y,
    const float* __restrict__ theta, const float* __restrict__ rot,
    float* __restrict__ per_batch) {
    __shared__ float buf[NPTS];   // 16 KiB — publish buffer only

    const int t = threadIdx.x & 63;       // wave lane
    const int wave = threadIdx.x >> 6;    // 0: x, 1: y
    const int p = blockIdx.x;
    const int b = blockIdx.y;

    const float t0 = theta[p * 3 + 0], t1 = theta[p * 3 + 1], t2 = theta[p * 3 + 2];
    const float* R = rot + b * 9;
    const float p0 = t0 * R[0] + t1 * R[3] + t2 * R[6];
    const float p1 = t0 * R[1] + t1 * R[4] + t2 * R[7];
    const float p2 = t0 * R[2] + t1 * R[5] + t2 * R[8];

    const float* src = wave ? y : x;

    // Each wave sorts its own array, completely barrier- and LDS-free.
    float v[V];
    load_project(src + (size_t)b * NPTS * 3 + (size_t)t * V * 3, v, p0, p1, p2);
    sort4096(v, t);

    const int t15 = t & 15;
    // Wave 1 publishes sorted y; wave 0 then diffs.
    if (wave == 1) write_own(buf, v, t, t15);
    __syncthreads();

    if (wave == 0) {
        float w[V];
        read_own(buf, w, t, t15);
        float s = 0.0f;
#pragma unroll
        for (int r = 0; r < V; ++r) {
            const float d = v[r] - w[r];
            s += d * d;
        }
        for (int off = 32; off > 0; off >>= 1) s += __shfl_down(s, off, 64);
        if (t == 0) atomicAdd(&per_batch[b], s);
    }
}

__global__ void finalize_kernel(const float* __restrict__ per_batch, float* __restrict__ out) {
    const int t = threadIdx.x;  // 64 threads
    float v = (t < NBATCH) ? sqrtf(per_batch[t] * (1.0f / (float)NPROJ)) : 0.0f;
    for (int off = 32; off > 0; off >>= 1) v += __shfl_down(v, off, 64);
    if (t == 0) out[0] = v * (1.0f / (float)NBATCH);
}

extern "C" void kernel_launch(void* const* d_in, const int* in_sizes, int n_in,
                              void* d_out, int out_size, void* d_ws, size_t ws_size,
                              hipStream_t stream) {
    const float* x = (const float*)d_in[0];
    const float* y = (const float*)d_in[1];
    const float* theta = (const float*)d_in[2];
    const float* rot = (const float*)d_in[3];
    float* per_batch = (float*)d_ws;
    float* out = (float*)d_out;

    hipMemsetAsync(per_batch, 0, NBATCH * sizeof(float), stream);

    dim3 grid(NPROJ, NBATCH);
    swd_kernel<<<grid, BLK, 0, stream>>>(x, y, theta, rot, per_batch);

    finalize_kernel<<<1, 64, 0, stream>>>(per_batch, out);
}

// Round 6
// 352.093 us; speedup vs baseline: 2.8405x; 1.0369x over previous
//
#include <hip/hip_runtime.h>
#include <math.h>

#define NPTS 4096
#define BLK 128
#define V 64
#define NPROJ 256
#define NBATCH 32

// R13: R12 (LDS-free shfl-bitonic sort, verified) + three fixes targeting the
// AGPR-shuttle tax R12's counters exposed:
//   VGPR_Count=56 (< v[64]!) with zero scratch traffic => v[] lived in AGPRs;
//   plain VALU can't source AGPRs, so every cmpex paid accvgpr_read/write.
//   Measured VALU-busy 284us vs ~108us op-count floor (2.6x inflation).
//   Allocator targeted LDS-implied 5 waves/EU (102 regs: 56 VGPR + ~46 AGPR)
//   though LDS actually binds at ~3.5 waves/EU (14 waves/CU measured, 41%).
// Fixes:
//  1. amdgpu_waves_per_eu(2,4): cap occupancy target at 4/EU -> 128-reg
//     budget, no AGPR squeeze. LDS binds at ~3.5/EU anyway: zero occ loss.
//  2. Tail diff fused (no w[64] array): epilogue peak pressure ~90, not 128+.
//  3. Cross-lane keep as compare-select ((q<v)!=hi ? q : v): lowers to
//     v_cmp + s_xor_b64(lane-mask, free SALU pipe) + v_cndmask = 2 VALU/elem
//     vs fmin+fmax+cndmask = 3 VALU/elem. Saves ~1408 VALU ops/sort (~15%).
// Sort network unchanged from R12 (verified, absmax 0.0):
//   layout A (element idx = lane*64 + reg); merges 2..64 in-reg;
//   merge m>=128: rev_shfl<(m-1)>>6>, stage_shfl<j>>6> j=m/4..64,
//   stages<32,1> in-reg. LDS = one 16 KiB publish buffer only.

__device__ __forceinline__ void cmpex_asc(float& a, float& b) {
    const float lo = fminf(a, b), hi = fmaxf(a, b);
    a = lo; b = hi;
}

template<int JB, int JL>
__device__ __forceinline__ void stages(float* v) {
#pragma unroll
    for (int r = 0; r < V; ++r)
        if ((r & JB) == 0) cmpex_asc(v[r], v[r | JB]);
    if constexpr (JB > JL) stages<(JB >> 1), JL>(v);
}

template<int MASK>
__device__ __forceinline__ void rev_inreg(float* v) {
    constexpr int S = (MASK + 1) >> 1;
#pragma unroll
    for (int r = 0; r < V; ++r) {
        if ((r & S) == 0) {
            const float a = v[r], b = v[r ^ MASK];
            v[r] = fminf(a, b);
            v[r ^ MASK] = fmaxf(a, b);
        }
    }
}

// Keep-side select: hi lanes keep max, lo lanes keep min, of (mine, q).
// ((q < mine) != hi) ? q : mine  ==  hi ? max : min   (ties keep mine).
// Lowers to v_cmp + s_xor_b64 (hi is a loop-invariant lane-mask) + v_cndmask.
__device__ __forceinline__ float keep(float mine, float q, bool hi) {
    return ((q < mine) != hi) ? q : mine;
}

// Reversal across thread-pair (xor XM), registers reversed (r <-> 63-r).
// Element (t, r) exchanges with (t^XM, 63-r); hi lanes keep max.
template<int XM>
__device__ __forceinline__ void rev_shfl(float* v, bool hi) {
#pragma unroll
    for (int r = 0; r < 32; ++r) {
        const float pa = __shfl_xor(v[63 - r], XM, 64);
        const float pb = __shfl_xor(v[r], XM, 64);
        v[r]      = keep(v[r],      pa, hi);
        v[63 - r] = keep(v[63 - r], pb, hi);
    }
}
// Same-register cross-thread stage (xor XM).
template<int XM>
__device__ __forceinline__ void stage_shfl(float* v, bool hi) {
#pragma unroll
    for (int r = 0; r < V; ++r) {
        const float q = __shfl_xor(v[r], XM, 64);
        v[r] = keep(v[r], q, hi);
    }
}

// Natural (own-slot) publish write, float4-slot = (t<<4)|(c^t15)
// (bank-spreading XOR placement: 2 lanes/bank per instr = conflict-free).
__device__ __forceinline__ void write_own(float* s, const float* v, int t, int t15) {
    float4* s4 = (float4*)s;
#pragma unroll
    for (int c = 0; c < 16; ++c)
        s4[(t << 4) | (c ^ t15)] =
            make_float4(v[4*c], v[4*c+1], v[4*c+2], v[4*c+3]);
}

__device__ __forceinline__ void load_project(const float* base, float* v,
                                             float p0, float p1, float p2) {
    const float4* b4 = (const float4*)base;
#pragma unroll
    for (int g = 0; g < 16; ++g) {
        float4 a = b4[g * 3 + 0], c = b4[g * 3 + 1], d = b4[g * 3 + 2];
        v[4*g+0] = a.x * p0 + a.y * p1 + a.z * p2;
        v[4*g+1] = a.w * p0 + c.x * p1 + c.y * p2;
        v[4*g+2] = c.z * p0 + c.w * p1 + d.x * p2;
        v[4*g+3] = d.y * p0 + d.z * p1 + d.w * p2;
    }
}

// Full ascending sort of 4096 floats held as v[64] per thread, layout A
// (element idx = t*64 + r). Pure in-register + cross-lane; no LDS.
__device__ __forceinline__ void sort4096(float* v, int t) {
    const bool hi1  = (t & 1) != 0;
    const bool hi2  = (t & 2) != 0;
    const bool hi4  = (t & 4) != 0;
    const bool hi8  = (t & 8) != 0;
    const bool hi16 = (t & 16) != 0;
    const bool hi32 = (t & 32) != 0;

    // merges 2..64: fully in-register
    rev_inreg<1>(v);
    rev_inreg<3>(v);  stages<1, 1>(v);
    rev_inreg<7>(v);  stages<2, 1>(v);
    rev_inreg<15>(v); stages<4, 1>(v);
    rev_inreg<31>(v); stages<8, 1>(v);
    rev_inreg<63>(v); stages<16, 1>(v);

    // merge 128
    rev_shfl<1>(v, hi1);
    stages<32, 1>(v);

    // merge 256
    rev_shfl<3>(v, hi2);
    stage_shfl<2>(v, hi2);
    stage_shfl<1>(v, hi1);
    stages<32, 1>(v);

    // merge 512
    rev_shfl<7>(v, hi4);
    stage_shfl<2>(v, hi2);
    stage_shfl<1>(v, hi1);
    stages<32, 1>(v);

    // merge 1024
    rev_shfl<15>(v, hi8);
    stage_shfl<4>(v, hi4);
    stage_shfl<2>(v, hi2);
    stage_shfl<1>(v, hi1);
    stages<32, 1>(v);

    // merge 2048
    rev_shfl<31>(v, hi16);
    stage_shfl<8>(v, hi8);
    stage_shfl<4>(v, hi4);
    stage_shfl<2>(v, hi2);
    stage_shfl<1>(v, hi1);
    stages<32, 1>(v);

    // merge 4096
    rev_shfl<63>(v, hi32);
    stage_shfl<16>(v, hi16);
    stage_shfl<8>(v, hi8);
    stage_shfl<4>(v, hi4);
    stage_shfl<2>(v, hi2);
    stage_shfl<1>(v, hi1);
    stages<32, 1>(v);
}

__global__ __launch_bounds__(BLK)
__attribute__((amdgpu_waves_per_eu(2, 4)))
void swd_kernel(
    const float* __restrict__ x, const float* __restrict__ y,
    const float* __restrict__ theta, const float* __restrict__ rot,
    float* __restrict__ per_batch) {
    __shared__ float buf[NPTS];   // 16 KiB — publish buffer only

    const int t = threadIdx.x & 63;       // wave lane
    const int wave = threadIdx.x >> 6;    // 0: x, 1: y
    const int p = blockIdx.x;
    const int b = blockIdx.y;

    const float t0 = theta[p * 3 + 0], t1 = theta[p * 3 + 1], t2 = theta[p * 3 + 2];
    const float* R = rot + b * 9;
    const float p0 = t0 * R[0] + t1 * R[3] + t2 * R[6];
    const float p1 = t0 * R[1] + t1 * R[4] + t2 * R[7];
    const float p2 = t0 * R[2] + t1 * R[5] + t2 * R[8];

    const float* src = wave ? y : x;

    // Each wave sorts its own array, completely barrier- and LDS-free.
    float v[V];
    load_project(src + (size_t)b * NPTS * 3 + (size_t)t * V * 3, v, p0, p1, p2);
    sort4096(v, t);

    const int t15 = t & 15;
    // Wave 1 publishes sorted y; wave 0 then diffs.
    if (wave == 1) write_own(buf, v, t, t15);
    __syncthreads();

    if (wave == 0) {
        // Fused read+diff: w never materializes (epilogue pressure ~v[64]+8).
        const float4* s4 = (const float4*)buf;
        float s = 0.0f;
#pragma unroll
        for (int c = 0; c < 16; ++c) {
            const float4 f = s4[(t << 4) | (c ^ t15)];
            const float d0 = v[4*c+0] - f.x;
            const float d1 = v[4*c+1] - f.y;
            const float d2 = v[4*c+2] - f.z;
            const float d3 = v[4*c+3] - f.w;
            s += d0 * d0 + d1 * d1 + d2 * d2 + d3 * d3;
        }
        for (int off = 32; off > 0; off >>= 1) s += __shfl_down(s, off, 64);
        if (t == 0) atomicAdd(&per_batch[b], s);
    }
}

__global__ void finalize_kernel(const float* __restrict__ per_batch, float* __restrict__ out) {
    const int t = threadIdx.x;  // 64 threads
    float v = (t < NBATCH) ? sqrtf(per_batch[t] * (1.0f / (float)NPROJ)) : 0.0f;
    for (int off = 32; off > 0; off >>= 1) v += __shfl_down(v, off, 64);
    if (t == 0) out[0] = v * (1.0f / (float)NBATCH);
}

extern "C" void kernel_launch(void* const* d_in, const int* in_sizes, int n_in,
                              void* d_out, int out_size, void* d_ws, size_t ws_size,
                              hipStream_t stream) {
    const float* x = (const float*)d_in[0];
    const float* y = (const float*)d_in[1];
    const float* theta = (const float*)d_in[2];
    const float* rot = (const float*)d_in[3];
    float* per_batch = (float*)d_ws;
    float* out = (float*)d_out;

    hipMemsetAsync(per_batch, 0, NBATCH * sizeof(float), stream);

    dim3 grid(NPROJ, NBATCH);
    swd_kernel<<<grid, BLK, 0, stream>>>(x, y, theta, rot, per_batch);

    finalize_kernel<<<1, 64, 0, stream>>>(per_batch, out);
}